// Round 2
// baseline (237.717 us; speedup 1.0000x reference)
//
#include <hip/hip_runtime.h>
#include <math.h>

#define NPROB (64 * 2048)

__host__ __device__ constexpr int TRI(int i, int j) { return i * 13 - i * (i - 1) / 2 + (j - i); }
__host__ __device__ constexpr int OI6(int i, int j) { return i * 6 - i * (i - 1) / 2 + (j - i); }
__host__ __device__ constexpr int QI(int i, int j)  { return i * 7 - i * (i - 1) / 2 + (j - i); }

// M fetch from the symmetric triangle held in registers. r,c MUST be
// compile-time constants (fully unrolled loops) or mreg spills to scratch.
#define MD(r, c) ((double)mreg[((r) < (c)) ? TRI((r), (c)) : TRI((c), (r))])

__global__ __launch_bounds__(256) void gn5_kernel(const float* __restrict__ Mg,
                                                  const float* __restrict__ Tg,
                                                  float* __restrict__ outg) {
    const int tid  = threadIdx.x;
    const int lane = tid & 63;
    const int wv   = tid >> 6;
    const long long prob = (long long)blockIdx.x * 256 + tid;

    // Stage 64 problems (64*169 floats = 43.3 KB) at a time; each wave then
    // pulls its own symmetric triangle (91 fp32) into registers.
    __shared__ __align__(16) float buf[64 * 169];
    float mreg[91];

    #pragma unroll 1
    for (int w = 0; w < 4; ++w) {
        const long long c0 = (long long)blockIdx.x * 256 + (long long)w * 64;
        const float4* src = (const float4*)(Mg + c0 * 169);
        float4* dst = (float4*)buf;
        #pragma unroll 1
        for (int i = tid; i < (64 * 169) / 4; i += 256) dst[i] = src[i];
        __syncthreads();
        if (wv == w) {
            #pragma unroll
            for (int i = 0; i < 13; ++i)
                #pragma unroll
                for (int j = i; j < 13; ++j)
                    mreg[TRI(i, j)] = buf[lane * 169 + i * 13 + j];
        }
        __syncthreads();
    }

    // T rows 0..2 (bottom row is (0,0,0,1) and stays so under T@expm).
    double t[3][4];
    {
        const float* tp = Tg + prob * 16;
        #pragma unroll
        for (int i = 0; i < 3; ++i)
            #pragma unroll
            for (int j = 0; j < 4; ++j)
                t[i][j] = (double)tp[i * 4 + j];
    }

    double q[28];  // symmetric 7x7 upper triangle of Q / Omega

    #pragma unroll 1
    for (int it = 0; it < 5; ++it) {
        // ===== Q = P^T M P via P's block structure =====
        // P rows: 3i+r (i,r in 0..2): [skew(t_i)[r,:] | 0 | t_i[r]]
        //         row 9:              [0 ... 0 | 1]
        //         rows 10+i:          [0 0 0 | t[i][0..2] | t[i][3]]

        // ---- y6 = M * p6, p6 = (t00..t22, 1, d0,d1,d2) ----
        double p6[13];
        #pragma unroll
        for (int i = 0; i < 3; ++i) {
            p6[3 * i + 0] = t[i][0];
            p6[3 * i + 1] = t[i][1];
            p6[3 * i + 2] = t[i][2];
            p6[10 + i]    = t[i][3];
        }
        p6[9] = 1.0;
        double y6[13];
        #pragma unroll
        for (int r = 0; r < 13; ++r) y6[r] = 0.0;
        #pragma unroll
        for (int i = 0; i < 13; ++i)
            #pragma unroll
            for (int j = i; j < 13; ++j) {
                const double m = MD(i, j);
                y6[i] += m * p6[j];
                if (i < j) y6[j] += m * p6[i];
            }

        // ---- Q66 = p6 . y6 ; QB6 = R^T y6[10:13] ; QA6 = sum_i cross(y6_i, t_i)
        double q66 = 0.0;
        #pragma unroll
        for (int r = 0; r < 13; ++r) q66 += p6[r] * y6[r];

        double qa6[3] = {0.0, 0.0, 0.0};
        #pragma unroll
        for (int i = 0; i < 3; ++i) {
            const double v0 = y6[3 * i + 0], v1 = y6[3 * i + 1], v2 = y6[3 * i + 2];
            qa6[0] += v1 * t[i][2] - v2 * t[i][1];
            qa6[1] += v2 * t[i][0] - v0 * t[i][2];
            qa6[2] += v0 * t[i][1] - v1 * t[i][0];
        }
        double qb6[3] = {0.0, 0.0, 0.0};
        #pragma unroll
        for (int i = 0; i < 3; ++i) {
            const double yv = y6[10 + i];
            qb6[0] += t[i][0] * yv;
            qb6[1] += t[i][1] * yv;
            qb6[2] += t[i][2] * yv;
        }

        // ---- Q_BB = R^T Mt R, Mt = M[10:13,10:13] ----
        double qbb[3][3];
        {
            const double mt00 = MD(10, 10), mt01 = MD(10, 11), mt02 = MD(10, 12);
            const double mt11 = MD(11, 11), mt12 = MD(11, 12), mt22 = MD(12, 12);
            double wb[3][3];
            #pragma unroll
            for (int jj = 0; jj < 3; ++jj) {
                wb[0][jj] = mt00 * t[0][jj] + mt01 * t[1][jj] + mt02 * t[2][jj];
                wb[1][jj] = mt01 * t[0][jj] + mt11 * t[1][jj] + mt12 * t[2][jj];
                wb[2][jj] = mt02 * t[0][jj] + mt12 * t[1][jj] + mt22 * t[2][jj];
            }
            #pragma unroll
            for (int k = 0; k < 3; ++k)
                #pragma unroll
                for (int l = k; l < 3; ++l)
                    qbb[k][l] = t[0][k] * wb[0][l] + t[1][k] * wb[1][l] + t[2][k] * wb[2][l];
        }

        // ---- Q_AB = sum_i K_i^T (M[3i:3i+3,10:13] R) ----
        double qab[3][3];
        #pragma unroll
        for (int k = 0; k < 3; ++k)
            #pragma unroll
            for (int jj = 0; jj < 3; ++jj) qab[k][jj] = 0.0;
        #pragma unroll
        for (int i = 0; i < 3; ++i) {
            double W[3][3];
            #pragma unroll
            for (int r = 0; r < 3; ++r) {
                const double m0 = MD(3 * i + r, 10);
                const double m1 = MD(3 * i + r, 11);
                const double m2 = MD(3 * i + r, 12);
                #pragma unroll
                for (int jj = 0; jj < 3; ++jj)
                    W[r][jj] = m0 * t[0][jj] + m1 * t[1][jj] + m2 * t[2][jj];
            }
            const double ix = t[i][0], iy = t[i][1], iz = t[i][2];
            #pragma unroll
            for (int jj = 0; jj < 3; ++jj) {
                qab[0][jj] += W[1][jj] * iz - W[2][jj] * iy;
                qab[1][jj] += W[2][jj] * ix - W[0][jj] * iz;
                qab[2][jj] += W[0][jj] * iy - W[1][jj] * ix;
            }
        }

        // ---- Q_AA = sum_{i,j} K_i^T M_ij K_j (use symmetry: i<=j, add Z+Z^T for i<j)
        double qaa[3][3];
        #pragma unroll
        for (int k = 0; k < 3; ++k)
            #pragma unroll
            for (int l = 0; l < 3; ++l) qaa[k][l] = 0.0;
        #pragma unroll
        for (int i = 0; i < 3; ++i)
            #pragma unroll
            for (int j = i; j < 3; ++j) {
                const double jx = t[j][0], jy = t[j][1], jz = t[j][2];
                double X[3][3];  // M_ij * skew(t_j)
                #pragma unroll
                for (int r = 0; r < 3; ++r) {
                    const double m0 = MD(3 * i + r, 3 * j + 0);
                    const double m1 = MD(3 * i + r, 3 * j + 1);
                    const double m2 = MD(3 * i + r, 3 * j + 2);
                    X[r][0] = m1 * jz - m2 * jy;
                    X[r][1] = m2 * jx - m0 * jz;
                    X[r][2] = m0 * jy - m1 * jx;
                }
                const double ix = t[i][0], iy = t[i][1], iz = t[i][2];
                double Z[3][3];  // K_i^T X : Z[:,l] = cross(X[:,l], t_i)
                #pragma unroll
                for (int l = 0; l < 3; ++l) {
                    Z[0][l] = X[1][l] * iz - X[2][l] * iy;
                    Z[1][l] = X[2][l] * ix - X[0][l] * iz;
                    Z[2][l] = X[0][l] * iy - X[1][l] * ix;
                }
                #pragma unroll
                for (int k = 0; k < 3; ++k)
                    #pragma unroll
                    for (int l = k; l < 3; ++l)
                        qaa[k][l] += (i == j) ? Z[k][l] : (Z[k][l] + Z[l][k]);
            }

        // ---- assemble q (upper triangle of 7x7) ----
        #pragma unroll
        for (int k = 0; k < 3; ++k) {
            #pragma unroll
            for (int l = k; l < 3; ++l) q[QI(k, l)] = qaa[k][l];
            #pragma unroll
            for (int l = 0; l < 3; ++l) q[QI(k, 3 + l)] = qab[k][l];
            q[QI(k, 6)] = qa6[k];
        }
        #pragma unroll
        for (int k = 0; k < 3; ++k) {
            #pragma unroll
            for (int l = k; l < 3; ++l) q[QI(3 + k, 3 + l)] = qbb[k][l];
            q[QI(3 + k, 6)] = qb6[k];
        }
        q[QI(6, 6)] = q66;

        // ---- regularization: Omega = Q[0:6,0:6] + diag(10,10,10,regT,regT,regT)
        const double trQ  = q[QI(3, 3)] + q[QI(4, 4)] + q[QI(5, 5)];
        const double regT = 1e-8 * fmax(trQ, 1.0);
        q[QI(0, 0)] += 10.0;
        q[QI(1, 1)] += 10.0;
        q[QI(2, 2)] += 10.0;
        q[QI(3, 3)] += regT;
        q[QI(4, 4)] += regT;
        q[QI(5, 5)] += regT;

        // ---- _inv's extra reg: 1e-5 * (1 + max(Omega)) (signed max, full 6x6) ----
        double mx = q[QI(0, 0)];
        #pragma unroll
        for (int k = 0; k < 6; ++k)
            #pragma unroll
            for (int l = k; l < 6; ++l)
                mx = fmax(mx, q[QI(k, l)]);
        const double reg2 = 1e-5 * (1.0 + mx);

        // ---- solve (Omega + reg2*I) x = g,  v = -x  (symmetric GE, SPD) ----
        double w[21], bb[6], dinv[6];
        #pragma unroll
        for (int k = 0; k < 6; ++k) {
            #pragma unroll
            for (int l = k; l < 6; ++l) w[OI6(k, l)] = q[QI(k, l)];
            w[OI6(k, k)] += reg2;
            bb[k] = q[QI(k, 6)];
        }
        #pragma unroll
        for (int k = 0; k < 6; ++k) {
            const double inv = 1.0 / w[OI6(k, k)];
            dinv[k] = inv;
            #pragma unroll
            for (int i = k + 1; i < 6; ++i) {
                const double f = w[OI6(k, i)] * inv;
                #pragma unroll
                for (int j = i; j < 6; ++j) w[OI6(i, j)] -= f * w[OI6(k, j)];
                bb[i] -= f * bb[k];
            }
        }
        double x[6];
        #pragma unroll
        for (int i = 5; i >= 0; --i) {
            double s = bb[i];
            #pragma unroll
            for (int j = i + 1; j < 6; ++j) s -= w[OI6(i, j)] * x[j];
            x[i] = s * dinv[i];
        }
        const double wx = -x[0], wy = -x[1], wz = -x[2];
        const double ux = -x[3], uy = -x[4], uz = -x[5];

        // ---- closed-form expm of se(3): E = [[R, V*u],[0,1]] ----
        const double tsq = wx * wx + wy * wy + wz * wz;
        double A, B, Cc;
        if (tsq < 1.0) {
            // Taylor in theta^2; with terms through tsq^8 this is fp64-exact
            // (next term < 1e-17) for tsq < 1.
            A  = 1.0 + tsq * (-1.0/6 + tsq * (1.0/120 + tsq * (-1.0/5040 + tsq * (1.0/362880
                 + tsq * (-1.0/39916800.0 + tsq * (1.0/6227020800.0 + tsq * (-1.0/1307674368000.0
                 + tsq * (1.0/355687428096000.0))))))));
            B  = 0.5 + tsq * (-1.0/24 + tsq * (1.0/720 + tsq * (-1.0/40320 + tsq * (1.0/3628800
                 + tsq * (-1.0/479001600.0 + tsq * (1.0/87178291200.0 + tsq * (-1.0/20922789888000.0
                 + tsq * (1.0/6402373705728000.0))))))));
            Cc = 1.0/6 + tsq * (-1.0/120 + tsq * (1.0/5040 + tsq * (-1.0/362880 + tsq * (1.0/39916800.0
                 + tsq * (-1.0/6227020800.0 + tsq * (1.0/1307674368000.0 + tsq * (-1.0/355687428096000.0
                 + tsq * (1.0/121645100408832000.0))))))));
        } else {
            const double th = sqrt(tsq);
            const double s = sin(th), c = cos(th);
            A  = s / th;
            B  = (1.0 - c) / tsq;
            Cc = (th - s) / (tsq * th);
        }
        // K^2 = w w^T - tsq*I
        const double K2xx = wx * wx - tsq, K2yy = wy * wy - tsq, K2zz = wz * wz - tsq;
        const double K2xy = wx * wy, K2xz = wx * wz, K2yz = wy * wz;
        double R[3][3];
        R[0][0] = 1.0 + B * K2xx;      R[0][1] = -A * wz + B * K2xy;  R[0][2] =  A * wy + B * K2xz;
        R[1][0] =  A * wz + B * K2xy;  R[1][1] = 1.0 + B * K2yy;      R[1][2] = -A * wx + B * K2yz;
        R[2][0] = -A * wy + B * K2xz;  R[2][1] =  A * wx + B * K2yz;  R[2][2] = 1.0 + B * K2zz;
        const double V00 = 1.0 + Cc * K2xx,      V01 = -B * wz + Cc * K2xy, V02 =  B * wy + Cc * K2xz;
        const double V10 =  B * wz + Cc * K2xy,  V11 = 1.0 + Cc * K2yy,     V12 = -B * wx + Cc * K2yz;
        const double V20 = -B * wy + Cc * K2xz,  V21 =  B * wx + Cc * K2yz, V22 = 1.0 + Cc * K2zz;
        const double ex = V00 * ux + V01 * uy + V02 * uz;
        const double ey = V10 * ux + V11 * uy + V12 * uz;
        const double ez = V20 * ux + V21 * uy + V22 * uz;

        // ---- T = T @ E ----
        #pragma unroll
        for (int i = 0; i < 3; ++i) {
            const double a0 = t[i][0], a1 = t[i][1], a2 = t[i][2], a3 = t[i][3];
            t[i][0] = a0 * R[0][0] + a1 * R[1][0] + a2 * R[2][0];
            t[i][1] = a0 * R[0][1] + a1 * R[1][1] + a2 * R[2][1];
            t[i][2] = a0 * R[0][2] + a1 * R[1][2] + a2 * R[2][2];
            t[i][3] = a0 * ex + a1 * ey + a2 * ez + a3;
        }
        // q holds Omega (with diag d, without reg2) for the epilogue.
    }

    // ---- outputs: T [NPROB,4,4] then Omega/(tz^2+1e-8) [NPROB,6,6], fp32 ----
    {
        float* to = outg + prob * 16;
        #pragma unroll
        for (int i = 0; i < 3; ++i)
            #pragma unroll
            for (int j = 0; j < 4; ++j)
                to[i * 4 + j] = (float)t[i][j];
        to[12] = 0.0f; to[13] = 0.0f; to[14] = 0.0f; to[15] = 1.0f;

        const double invden = 1.0 / (t[2][3] * t[2][3] + 1e-8);
        float* oo = outg + (long long)NPROB * 16 + prob * 36;
        #pragma unroll
        for (int k = 0; k < 6; ++k)
            #pragma unroll
            for (int l = 0; l < 6; ++l)
                oo[k * 6 + l] = (float)(q[(k <= l) ? QI(k, l) : QI(l, k)] * invden);
    }
}

extern "C" void kernel_launch(void* const* d_in, const int* in_sizes, int n_in,
                              void* d_out, int out_size, void* d_ws, size_t ws_size,
                              hipStream_t stream) {
    const float* Mg = (const float*)d_in[0];  // [64,2048,13,13] fp32
    const float* Tg = (const float*)d_in[1];  // [64,2048,4,4]  fp32
    float* out = (float*)d_out;               // [NPROB*16 + NPROB*36] fp32
    (void)in_sizes; (void)n_in; (void)out_size; (void)d_ws; (void)ws_size;

    const int threads = 256;
    const int blocks = NPROB / threads;  // 512
    gn5_kernel<<<blocks, threads, 0, stream>>>(Mg, Tg, out);
}

// Round 3
// 202.905 us; speedup vs baseline: 1.1716x; 1.1716x over previous
//
#include <hip/hip_runtime.h>
#include <math.h>

#define NPROB (64 * 2048)

__host__ __device__ constexpr int TRI(int i, int j) { return i * 13 - i * (i - 1) / 2 + (j - i); }
__host__ __device__ constexpr int OI6(int i, int j) { return i * 6 - i * (i - 1) / 2 + (j - i); }
__host__ __device__ constexpr int QI(int i, int j)  { return i * 7 - i * (i - 1) / 2 + (j - i); }

__global__ __launch_bounds__(256) void gn5_kernel(const float* __restrict__ Mg,
                                                  const float* __restrict__ Tg,
                                                  float* __restrict__ outg) {
    const int tid  = threadIdx.x;
    const int lane = tid & 63;
    const int wv   = tid >> 6;
    const long long prob = (long long)blockIdx.x * 256 + tid;

    // Stage 64 problems (64*169 floats = 43.3 KB) at a time; each wave then
    // pulls its own symmetric triangle (91 fp32) into registers.
    __shared__ __align__(16) float buf[64 * 169];
    float mreg[91];

    #pragma unroll 1
    for (int w = 0; w < 4; ++w) {
        const long long c0 = (long long)blockIdx.x * 256 + (long long)w * 64;
        const float4* src = (const float4*)(Mg + c0 * 169);
        float4* dst = (float4*)buf;
        #pragma unroll 1
        for (int i = tid; i < (64 * 169) / 4; i += 256) dst[i] = src[i];
        __syncthreads();
        if (wv == w) {
            #pragma unroll
            for (int i = 0; i < 13; ++i)
                #pragma unroll
                for (int j = i; j < 13; ++j)
                    mreg[TRI(i, j)] = buf[lane * 169 + i * 13 + j];
        }
        __syncthreads();
    }

    // T rows 0..2 (bottom row is (0,0,0,1) and stays so under T@expm).
    double t[3][4];
    {
        const float* tp = Tg + prob * 16;
        #pragma unroll
        for (int i = 0; i < 3; ++i)
            #pragma unroll
            for (int j = 0; j < 4; ++j)
                t[i][j] = (double)tp[i * 4 + j];
    }

    double q[28];  // symmetric 7x7 upper triangle of Q / Omega

    #pragma unroll 1
    for (int it = 0; it < 5; ++it) {
        // ===== Q = P^T M P, block-sweep: each M element cvt'd once/iter =====
        // p6 (P's 7th column) = (t00..t22, 1, d0,d1,d2); y6 = M * p6.
        double y6[13];
        #pragma unroll
        for (int r = 0; r < 13; ++r) y6[r] = 0.0;
        // zero the q entries we accumulate into (qaa, qab, qbb regions)
        #pragma unroll
        for (int k = 0; k < 3; ++k) {
            #pragma unroll
            for (int l = k; l < 3; ++l) q[QI(k, l)] = 0.0;
            #pragma unroll
            for (int l = 0; l < 3; ++l) q[QI(k, 3 + l)] = 0.0;
        }
        #pragma unroll
        for (int k = 0; k < 3; ++k)
            #pragma unroll
            for (int l = k; l < 3; ++l) q[QI(3 + k, 3 + l)] = 0.0;

        // ---- Phase 1: rot-rot blocks (i<=j): y6 dual-acc + Q_AA sandwich ----
        #pragma unroll
        for (int i = 0; i < 3; ++i)
            #pragma unroll
            for (int j = i; j < 3; ++j) {
                double md[3][3];
                if (i == j) {
                    #pragma unroll
                    for (int r = 0; r < 3; ++r)
                        #pragma unroll
                        for (int s = r; s < 3; ++s) {
                            const double v = (double)mreg[TRI(3 * i + r, 3 * i + s)];
                            md[r][s] = v; md[s][r] = v;
                        }
                    // y6 diag: y6[3i+r] += sum_s md[r][s] * t[i][s]
                    #pragma unroll
                    for (int r = 0; r < 3; ++r) {
                        double acc = y6[3 * i + r];
                        #pragma unroll
                        for (int s = 0; s < 3; ++s) acc += md[r][s] * t[i][s];
                        y6[3 * i + r] = acc;
                    }
                } else {
                    #pragma unroll
                    for (int r = 0; r < 3; ++r)
                        #pragma unroll
                        for (int s = 0; s < 3; ++s)
                            md[r][s] = (double)mreg[TRI(3 * i + r, 3 * j + s)];
                    // y6 dual: rows 3i+* get md*t_j, rows 3j+* get md^T*t_i
                    #pragma unroll
                    for (int r = 0; r < 3; ++r) {
                        double acc = y6[3 * i + r];
                        #pragma unroll
                        for (int s = 0; s < 3; ++s) acc += md[r][s] * t[j][s];
                        y6[3 * i + r] = acc;
                    }
                    #pragma unroll
                    for (int s = 0; s < 3; ++s) {
                        double acc = y6[3 * j + s];
                        #pragma unroll
                        for (int r = 0; r < 3; ++r) acc += md[r][s] * t[i][r];
                        y6[3 * j + s] = acc;
                    }
                }
                // X = md * K_j ; Z = K_i^T X ; qaa += Z (+ Z^T if i!=j)
                const double jx = t[j][0], jy = t[j][1], jz = t[j][2];
                double X[3][3];
                #pragma unroll
                for (int r = 0; r < 3; ++r) {
                    X[r][0] = md[r][1] * jz - md[r][2] * jy;
                    X[r][1] = md[r][2] * jx - md[r][0] * jz;
                    X[r][2] = md[r][0] * jy - md[r][1] * jx;
                }
                const double ix = t[i][0], iy = t[i][1], iz = t[i][2];
                double Z[3][3];
                #pragma unroll
                for (int l = 0; l < 3; ++l) {
                    Z[0][l] = X[1][l] * iz - X[2][l] * iy;
                    Z[1][l] = X[2][l] * ix - X[0][l] * iz;
                    Z[2][l] = X[0][l] * iy - X[1][l] * ix;
                }
                #pragma unroll
                for (int k = 0; k < 3; ++k)
                    #pragma unroll
                    for (int l = k; l < 3; ++l)
                        q[QI(k, l)] += (i == j) ? Z[k][l] : (Z[k][l] + Z[l][k]);
            }

        // ---- Phase 2: rot-trans blocks i=0..2 (cols 10..12): y6 + Q_AB ----
        #pragma unroll
        for (int i = 0; i < 3; ++i) {
            double md[3][3];
            #pragma unroll
            for (int r = 0; r < 3; ++r)
                #pragma unroll
                for (int s = 0; s < 3; ++s)
                    md[r][s] = (double)mreg[TRI(3 * i + r, 10 + s)];
            #pragma unroll
            for (int r = 0; r < 3; ++r) {
                double acc = y6[3 * i + r];
                #pragma unroll
                for (int s = 0; s < 3; ++s) acc += md[r][s] * t[s][3];
                y6[3 * i + r] = acc;
            }
            #pragma unroll
            for (int s = 0; s < 3; ++s) {
                double acc = y6[10 + s];
                #pragma unroll
                for (int r = 0; r < 3; ++r) acc += md[r][s] * t[i][r];
                y6[10 + s] = acc;
            }
            // W = md * R  (R rows are t[s][0..2]) ; qab += K_i^T W
            double W[3][3];
            #pragma unroll
            for (int r = 0; r < 3; ++r)
                #pragma unroll
                for (int jj = 0; jj < 3; ++jj)
                    W[r][jj] = md[r][0] * t[0][jj] + md[r][1] * t[1][jj] + md[r][2] * t[2][jj];
            const double ix = t[i][0], iy = t[i][1], iz = t[i][2];
            #pragma unroll
            for (int jj = 0; jj < 3; ++jj) {
                q[QI(0, 3 + jj)] += W[1][jj] * iz - W[2][jj] * iy;
                q[QI(1, 3 + jj)] += W[2][jj] * ix - W[0][jj] * iz;
                q[QI(2, 3 + jj)] += W[0][jj] * iy - W[1][jj] * ix;
            }
        }

        // ---- Phase 3: row/col 9 (the "ones" row): only feeds y6 ----
        #pragma unroll
        for (int r = 0; r < 9; ++r) {
            const double m = (double)mreg[TRI(r, 9)];
            y6[r] += m;                       // * p6[9] = 1
            y6[9] += m * t[r / 3][r % 3];     // p6[r]
        }
        y6[9] += (double)mreg[TRI(9, 9)];
        #pragma unroll
        for (int s = 0; s < 3; ++s) {
            const double m = (double)mreg[TRI(9, 10 + s)];
            y6[9] += m * t[s][3];
            y6[10 + s] += m;
        }

        // ---- Phase 4: trans-trans Mtt: y6 + Q_BB = R^T Mt R ----
        {
            double mt[3][3];
            #pragma unroll
            for (int r = 0; r < 3; ++r)
                #pragma unroll
                for (int s = r; s < 3; ++s) {
                    const double v = (double)mreg[TRI(10 + r, 10 + s)];
                    mt[r][s] = v; mt[s][r] = v;
                }
            #pragma unroll
            for (int r = 0; r < 3; ++r) {
                double acc = y6[10 + r];
                #pragma unroll
                for (int s = 0; s < 3; ++s) acc += mt[r][s] * t[s][3];
                y6[10 + r] = acc;
            }
            double wb[3][3];
            #pragma unroll
            for (int r = 0; r < 3; ++r)
                #pragma unroll
                for (int jj = 0; jj < 3; ++jj)
                    wb[r][jj] = mt[r][0] * t[0][jj] + mt[r][1] * t[1][jj] + mt[r][2] * t[2][jj];
            #pragma unroll
            for (int k = 0; k < 3; ++k)
                #pragma unroll
                for (int l = k; l < 3; ++l)
                    q[QI(3 + k, 3 + l)] += t[0][k] * wb[0][l] + t[1][k] * wb[1][l] + t[2][k] * wb[2][l];
        }

        // ---- Phase 5: last column of Q from y6 ----
        {
            double q66 = y6[9];
            #pragma unroll
            for (int i = 0; i < 3; ++i) {
                q66 += t[i][0] * y6[3 * i + 0] + t[i][1] * y6[3 * i + 1] + t[i][2] * y6[3 * i + 2];
                q66 += t[i][3] * y6[10 + i];
            }
            q[QI(6, 6)] = q66;
            double qa0 = 0.0, qa1 = 0.0, qa2 = 0.0;
            #pragma unroll
            for (int i = 0; i < 3; ++i) {
                const double v0 = y6[3 * i + 0], v1 = y6[3 * i + 1], v2 = y6[3 * i + 2];
                qa0 += v1 * t[i][2] - v2 * t[i][1];
                qa1 += v2 * t[i][0] - v0 * t[i][2];
                qa2 += v0 * t[i][1] - v1 * t[i][0];
            }
            q[QI(0, 6)] = qa0; q[QI(1, 6)] = qa1; q[QI(2, 6)] = qa2;
            #pragma unroll
            for (int k = 0; k < 3; ++k)
                q[QI(3 + k, 6)] = t[0][k] * y6[10] + t[1][k] * y6[11] + t[2][k] * y6[12];
        }

        // ---- regularization: Omega = Q[0:6,0:6] + diag(10,10,10,regT,regT,regT)
        const double trQ  = q[QI(3, 3)] + q[QI(4, 4)] + q[QI(5, 5)];
        const double regT = 1e-8 * fmax(trQ, 1.0);
        q[QI(0, 0)] += 10.0;
        q[QI(1, 1)] += 10.0;
        q[QI(2, 2)] += 10.0;
        q[QI(3, 3)] += regT;
        q[QI(4, 4)] += regT;
        q[QI(5, 5)] += regT;

        // ---- _inv's extra reg: 1e-5 * (1 + max(Omega)) (signed max, full 6x6) ----
        double mx = q[QI(0, 0)];
        #pragma unroll
        for (int k = 0; k < 6; ++k)
            #pragma unroll
            for (int l = k; l < 6; ++l)
                mx = fmax(mx, q[QI(k, l)]);
        const double reg2 = 1e-5 * (1.0 + mx);

        // ---- solve (Omega + reg2*I) x = g,  v = -x  (symmetric GE, SPD) ----
        double w[21], bb[6], dinv[6];
        #pragma unroll
        for (int k = 0; k < 6; ++k) {
            #pragma unroll
            for (int l = k; l < 6; ++l) w[OI6(k, l)] = q[QI(k, l)];
            w[OI6(k, k)] += reg2;
            bb[k] = q[QI(k, 6)];
        }
        #pragma unroll
        for (int k = 0; k < 6; ++k) {
            const double inv = 1.0 / w[OI6(k, k)];
            dinv[k] = inv;
            #pragma unroll
            for (int i = k + 1; i < 6; ++i) {
                const double f = w[OI6(k, i)] * inv;
                #pragma unroll
                for (int j = i; j < 6; ++j) w[OI6(i, j)] -= f * w[OI6(k, j)];
                bb[i] -= f * bb[k];
            }
        }
        double x[6];
        #pragma unroll
        for (int i = 5; i >= 0; --i) {
            double s = bb[i];
            #pragma unroll
            for (int j = i + 1; j < 6; ++j) s -= w[OI6(i, j)] * x[j];
            x[i] = s * dinv[i];
        }
        const double wx = -x[0], wy = -x[1], wz = -x[2];
        const double ux = -x[3], uy = -x[4], uz = -x[5];

        // ---- closed-form expm of se(3): E = [[R, V*u],[0,1]] ----
        const double tsq = wx * wx + wy * wy + wz * wz;
        double A, B, Cc;
        if (tsq < 1.0) {
            A  = 1.0 + tsq * (-1.0/6 + tsq * (1.0/120 + tsq * (-1.0/5040 + tsq * (1.0/362880
                 + tsq * (-1.0/39916800.0 + tsq * (1.0/6227020800.0 + tsq * (-1.0/1307674368000.0
                 + tsq * (1.0/355687428096000.0))))))));
            B  = 0.5 + tsq * (-1.0/24 + tsq * (1.0/720 + tsq * (-1.0/40320 + tsq * (1.0/3628800
                 + tsq * (-1.0/479001600.0 + tsq * (1.0/87178291200.0 + tsq * (-1.0/20922789888000.0
                 + tsq * (1.0/6402373705728000.0))))))));
            Cc = 1.0/6 + tsq * (-1.0/120 + tsq * (1.0/5040 + tsq * (-1.0/362880 + tsq * (1.0/39916800.0
                 + tsq * (-1.0/6227020800.0 + tsq * (1.0/1307674368000.0 + tsq * (-1.0/355687428096000.0
                 + tsq * (1.0/121645100408832000.0))))))));
        } else {
            const double th = sqrt(tsq);
            const double s = sin(th), c = cos(th);
            A  = s / th;
            B  = (1.0 - c) / tsq;
            Cc = (th - s) / (tsq * th);
        }
        const double K2xx = wx * wx - tsq, K2yy = wy * wy - tsq, K2zz = wz * wz - tsq;
        const double K2xy = wx * wy, K2xz = wx * wz, K2yz = wy * wz;
        double R[3][3];
        R[0][0] = 1.0 + B * K2xx;      R[0][1] = -A * wz + B * K2xy;  R[0][2] =  A * wy + B * K2xz;
        R[1][0] =  A * wz + B * K2xy;  R[1][1] = 1.0 + B * K2yy;      R[1][2] = -A * wx + B * K2yz;
        R[2][0] = -A * wy + B * K2xz;  R[2][1] =  A * wx + B * K2yz;  R[2][2] = 1.0 + B * K2zz;
        const double V00 = 1.0 + Cc * K2xx,      V01 = -B * wz + Cc * K2xy, V02 =  B * wy + Cc * K2xz;
        const double V10 =  B * wz + Cc * K2xy,  V11 = 1.0 + Cc * K2yy,     V12 = -B * wx + Cc * K2yz;
        const double V20 = -B * wy + Cc * K2xz,  V21 =  B * wx + Cc * K2yz, V22 = 1.0 + Cc * K2zz;
        const double ex = V00 * ux + V01 * uy + V02 * uz;
        const double ey = V10 * ux + V11 * uy + V12 * uz;
        const double ez = V20 * ux + V21 * uy + V22 * uz;

        // ---- T = T @ E ----
        #pragma unroll
        for (int i = 0; i < 3; ++i) {
            const double a0 = t[i][0], a1 = t[i][1], a2 = t[i][2], a3 = t[i][3];
            t[i][0] = a0 * R[0][0] + a1 * R[1][0] + a2 * R[2][0];
            t[i][1] = a0 * R[0][1] + a1 * R[1][1] + a2 * R[2][1];
            t[i][2] = a0 * R[0][2] + a1 * R[1][2] + a2 * R[2][2];
            t[i][3] = a0 * ex + a1 * ey + a2 * ez + a3;
        }
        // q holds Omega (with diag d, without reg2) for the epilogue.
    }

    // ---- outputs: T [NPROB,4,4] then Omega/(tz^2+1e-8) [NPROB,6,6], fp32 ----
    {
        float* to = outg + prob * 16;
        #pragma unroll
        for (int i = 0; i < 3; ++i)
            #pragma unroll
            for (int j = 0; j < 4; ++j)
                to[i * 4 + j] = (float)t[i][j];
        to[12] = 0.0f; to[13] = 0.0f; to[14] = 0.0f; to[15] = 1.0f;

        const double invden = 1.0 / (t[2][3] * t[2][3] + 1e-8);
        float* oo = outg + (long long)NPROB * 16 + prob * 36;
        #pragma unroll
        for (int k = 0; k < 6; ++k)
            #pragma unroll
            for (int l = 0; l < 6; ++l)
                oo[k * 6 + l] = (float)(q[(k <= l) ? QI(k, l) : QI(l, k)] * invden);
    }
}

extern "C" void kernel_launch(void* const* d_in, const int* in_sizes, int n_in,
                              void* d_out, int out_size, void* d_ws, size_t ws_size,
                              hipStream_t stream) {
    const float* Mg = (const float*)d_in[0];  // [64,2048,13,13] fp32
    const float* Tg = (const float*)d_in[1];  // [64,2048,4,4]  fp32
    float* out = (float*)d_out;               // [NPROB*16 + NPROB*36] fp32
    (void)in_sizes; (void)n_in; (void)out_size; (void)d_ws; (void)ws_size;

    const int threads = 256;
    const int blocks = NPROB / threads;  // 512
    gn5_kernel<<<blocks, threads, 0, stream>>>(Mg, Tg, out);
}